// Round 2
// baseline (1110.521 us; speedup 1.0000x reference)
//
#include <hip/hip_runtime.h>
#include <math.h>

typedef unsigned short u16;
typedef unsigned int u32;
typedef __attribute__((ext_vector_type(8))) short bf16x8;   // 8 bf16 in 4 VGPRs
typedef __attribute__((ext_vector_type(4))) float f32x4;

#define B_    32
#define N_    577
#define DIM_  768
#define HEADS_ 12
#define HD_   64
#define HID_  3072
#define MTOT_ (B_*N_)      // 18464
#define NP_   640          // padded key-length for v^T rows (covers 10*64 range)

// ---------- bf16 helpers (RNE) ----------
__device__ __forceinline__ u16 f2b(float f){
  u32 u = __builtin_bit_cast(u32, f);
  u += 0x7fffu + ((u >> 16) & 1u);
  return (u16)(u >> 16);
}
__device__ __forceinline__ float b2f(u16 h){
  return __builtin_bit_cast(float, (u32)h << 16);
}

// ---------- weight convert + transpose: w[K][N] fp32 -> wt[N][K] bf16 ----------
__global__ __launch_bounds__(256) void convT(const float* __restrict__ w,
                                             u16* __restrict__ wt, int K, int N){
  __shared__ float t[32][33];
  int n0 = blockIdx.x * 32, k0 = blockIdx.y * 32;
  int tx = threadIdx.x, ty = threadIdx.y;     // block (32,8)
  #pragma unroll
  for (int j = 0; j < 4; ++j)
    t[ty + j*8][tx] = w[(size_t)(k0 + ty + j*8) * N + n0 + tx];
  __syncthreads();
  #pragma unroll
  for (int j = 0; j < 4; ++j)
    wt[(size_t)(n0 + ty + j*8) * K + k0 + tx] = f2b(t[tx][ty + j*8]);
}

// ---------- LayerNorm row kernel: fp32 in -> bf16 out ----------
__global__ __launch_bounds__(256) void ln_k(const float* __restrict__ x,
                                            const float* __restrict__ g,
                                            const float* __restrict__ b,
                                            u16* __restrict__ out){
  int row = blockIdx.x, tid = threadIdx.x;
  const float* xr = x + (size_t)row * DIM_;
  float v0 = xr[tid], v1 = xr[tid + 256], v2 = xr[tid + 512];
  float s = v0 + v1 + v2;
  float s2 = v0*v0 + v1*v1 + v2*v2;
  #pragma unroll
  for (int m = 1; m < 64; m <<= 1){ s += __shfl_xor(s, m); s2 += __shfl_xor(s2, m); }
  __shared__ float ws[8];
  int wid = tid >> 6, ln = tid & 63;
  if (ln == 0){ ws[wid] = s; ws[4 + wid] = s2; }
  __syncthreads();
  s  = ws[0] + ws[1] + ws[2] + ws[3];
  s2 = ws[4] + ws[5] + ws[6] + ws[7];
  float mu = s * (1.0f / DIM_);
  float var = s2 * (1.0f / DIM_) - mu * mu;
  float rs = rsqrtf(var + 1e-5f);
  u16* orow = out + (size_t)row * DIM_;
  orow[tid]       = f2b((v0 - mu) * rs * g[tid]       + b[tid]);
  orow[tid + 256] = f2b((v1 - mu) * rs * g[tid + 256] + b[tid + 256]);
  orow[tid + 512] = f2b((v2 - mu) * rs * g[tid + 512] + b[tid + 512]);
}

// ---------- bt-GEMM: C[M][N] = A[M][K](bf16) * Bt[N][K](bf16)^T, fused epilogues ----------
// EPI 0: QKV scatter  | EPI 1: fp32 out = acc + bias + resid | EPI 2: bf16 out = gelu(acc+bias)
#define BM 128
#define BN 128
#define BK 32

template<int EPI>
__global__ __launch_bounds__(256) void gemm_bt(
    const u16* __restrict__ A, const u16* __restrict__ Bt,
    int M, int N, int K,
    const float* __restrict__ bias,
    const float* __restrict__ resid,
    float* __restrict__ outf,
    u16* __restrict__ outb,
    u16* __restrict__ qb, u16* __restrict__ kb, u16* __restrict__ vtb)
{
  __shared__ u16 Al[BM * BK];
  __shared__ u16 Bl[BN * BK];
  int tid = threadIdx.x;
  int wid = tid >> 6, l = tid & 63, ln = l & 15, sub = l >> 4;
  int wm = wid >> 1, wn = wid & 1;
  int tm = blockIdx.x, tn = blockIdx.y;

  f32x4 acc[4][4] = {};
  int arow = tid >> 2;            // 0..63
  int acol = (tid & 3) * 8;       // 0,8,16,24

  const int ktiles = K / BK;
  for (int kt = 0; kt < ktiles; ++kt){
    int kbase = kt * BK;
    #pragma unroll
    for (int i = 0; i < 2; ++i){
      int r = arow + i * 64;
      int gr = tm * BM + r; if (gr >= M) gr = M - 1;
      *(bf16x8*)&Al[r * BK + acol] = *(const bf16x8*)&A[(size_t)gr * K + kbase + acol];
      *(bf16x8*)&Bl[r * BK + acol] = *(const bf16x8*)&Bt[(size_t)(tn * BN + r) * K + kbase + acol];
    }
    __syncthreads();
    bf16x8 af[4], bfr[4];
    #pragma unroll
    for (int mi = 0; mi < 4; ++mi) af[mi]  = *(const bf16x8*)&Al[(wm*64 + mi*16 + ln) * BK + sub*8];
    #pragma unroll
    for (int ni = 0; ni < 4; ++ni) bfr[ni] = *(const bf16x8*)&Bl[(wn*64 + ni*16 + ln) * BK + sub*8];
    #pragma unroll
    for (int mi = 0; mi < 4; ++mi)
      #pragma unroll
      for (int ni = 0; ni < 4; ++ni)
        acc[mi][ni] = __builtin_amdgcn_mfma_f32_16x16x32_bf16(af[mi], bfr[ni], acc[mi][ni], 0, 0, 0);
    __syncthreads();
  }

  #pragma unroll
  for (int mi = 0; mi < 4; ++mi){
    int rbase = tm * BM + wm * 64 + mi * 16 + sub * 4;
    #pragma unroll
    for (int ni = 0; ni < 4; ++ni){
      int col = tn * BN + wn * 64 + ni * 16 + ln;
      #pragma unroll
      for (int r = 0; r < 4; ++r){
        int grow = rbase + r;
        if (grow >= M) continue;
        float val = acc[mi][ni][r];
        if (EPI == 0){
          u32 bb = (u32)grow / 577u;
          u32 nn = (u32)grow - bb * 577u;
          int which = col / 768;           // 0=q, 1=k, 2=v
          int rem = col - which * 768;     // col % 768 (768 is NOT pow2 -- no masking!)
          int hh = rem >> 6;
          int d  = col & 63;               // ok: 768 % 64 == 0
          if (which == 0)
            qb[(((size_t)bb * HEADS_ + hh) * N_ + nn) * HD_ + d] = f2b(val);
          else if (which == 1)
            kb[(((size_t)bb * HEADS_ + hh) * N_ + nn) * HD_ + d] = f2b(val);
          else
            vtb[(((size_t)bb * HEADS_ + hh) * HD_ + d) * NP_ + nn] = f2b(val);
        } else if (EPI == 1){
          outf[(size_t)grow * N + col] = val + bias[col] + resid[(size_t)grow * N + col];
        } else {
          float t = val + bias[col];
          float ge = 0.5f * t * (1.0f + erff(t * 0.70710678118654752f));
          outb[(size_t)grow * N + col] = f2b(ge);
        }
      }
    }
  }
}

// ---------- fused flash attention ----------
// grid: x = q-tile (10), y = b*h (384). 4 waves, each owns 16 q-rows.
__global__ __launch_bounds__(256) void attn_k(
    const u16* __restrict__ q, const u16* __restrict__ k,
    const u16* __restrict__ vt, const float* __restrict__ mask,
    u16* __restrict__ o)
{
  const float SCALE = 0.125f;
  int qt = blockIdx.x, bh = blockIdx.y;
  int tid = threadIdx.x;
  int wid = tid >> 6, l = tid & 63, ln = l & 15, sub = l >> 4;
  int b = bh / HEADS_, hh = bh - b * HEADS_;
  int qrow0 = qt * 64 + wid * 16;

  int qr = qrow0 + ln; if (qr > N_ - 1) qr = N_ - 1;
  const u16* qbase = q + ((size_t)bh * N_ + qr) * HD_;
  bf16x8 qf0 = *(const bf16x8*)&qbase[sub * 8];
  bf16x8 qf1 = *(const bf16x8*)&qbase[32 + sub * 8];

  f32x4 oacc[4] = {};
  float mrun[4] = {-1e30f, -1e30f, -1e30f, -1e30f};
  float lrun[4] = {0.f, 0.f, 0.f, 0.f};
  __shared__ u16 Pl[4][16 * 64];

  for (int mt = 0; mt < 10; ++mt){
    int mbase = mt * 64;
    f32x4 s[4];
    #pragma unroll
    for (int c = 0; c < 4; ++c){
      int kr = mbase + c * 16 + ln; if (kr > N_ - 1) kr = N_ - 1;
      const u16* kbase = k + ((size_t)bh * N_ + kr) * HD_;
      bf16x8 kf0 = *(const bf16x8*)&kbase[sub * 8];
      bf16x8 kf1 = *(const bf16x8*)&kbase[32 + sub * 8];
      f32x4 z = {};
      z = __builtin_amdgcn_mfma_f32_16x16x32_bf16(qf0, kf0, z, 0, 0, 0);
      z = __builtin_amdgcn_mfma_f32_16x16x32_bf16(qf1, kf1, z, 0, 0, 0);
      s[c] = z;
    }
    int qg0 = qrow0 + sub * 4;
    // scale * mask, bounds
    #pragma unroll
    for (int c = 0; c < 4; ++c){
      int mg = mbase + c * 16 + ln;
      #pragma unroll
      for (int r = 0; r < 4; ++r){
        if (mg < N_){
          int qgc = qg0 + r; if (qgc > N_ - 1) qgc = N_ - 1;
          s[c][r] = s[c][r] * SCALE * mask[(size_t)qgc * N_ + mg];
        } else {
          s[c][r] = -1e30f;
        }
      }
    }
    // online softmax (rows live across the 16-lane group)
    float pm[4];
    #pragma unroll
    for (int r = 0; r < 4; ++r)
      pm[r] = fmaxf(fmaxf(s[0][r], s[1][r]), fmaxf(s[2][r], s[3][r]));
    #pragma unroll
    for (int m = 1; m < 16; m <<= 1){
      #pragma unroll
      for (int r = 0; r < 4; ++r) pm[r] = fmaxf(pm[r], __shfl_xor(pm[r], m));
    }
    float alpha[4];
    #pragma unroll
    for (int r = 0; r < 4; ++r){
      float mnew = fmaxf(mrun[r], pm[r]);
      alpha[r] = __expf(mrun[r] - mnew);
      mrun[r] = mnew;
    }
    float ps[4] = {0.f, 0.f, 0.f, 0.f};
    #pragma unroll
    for (int c = 0; c < 4; ++c)
      #pragma unroll
      for (int r = 0; r < 4; ++r){
        float p = __expf(s[c][r] - mrun[r]);
        s[c][r] = p;
        ps[r] += p;
      }
    #pragma unroll
    for (int m = 1; m < 16; m <<= 1){
      #pragma unroll
      for (int r = 0; r < 4; ++r) ps[r] += __shfl_xor(ps[r], m);
    }
    #pragma unroll
    for (int r = 0; r < 4; ++r) lrun[r] = lrun[r] * alpha[r] + ps[r];
    // P -> LDS (per-wave), D-layout -> [q][m] row-major
    #pragma unroll
    for (int c = 0; c < 4; ++c)
      #pragma unroll
      for (int r = 0; r < 4; ++r)
        Pl[wid][(sub * 4 + r) * 64 + c * 16 + ln] = f2b(s[c][r]);
    // rescale O
    #pragma unroll
    for (int dt = 0; dt < 4; ++dt)
      #pragma unroll
      for (int r = 0; r < 4; ++r) oacc[dt][r] *= alpha[r];
    // PV
    #pragma unroll
    for (int half = 0; half < 2; ++half){
      bf16x8 pa = *(const bf16x8*)&Pl[wid][ln * 64 + half * 32 + sub * 8];
      #pragma unroll
      for (int dt = 0; dt < 4; ++dt){
        const u16* vb = vt + ((size_t)bh * HD_ + dt * 16 + ln) * NP_ + mbase + half * 32 + sub * 8;
        bf16x8 vf = *(const bf16x8*)vb;
        oacc[dt] = __builtin_amdgcn_mfma_f32_16x16x32_bf16(pa, vf, oacc[dt], 0, 0, 0);
      }
    }
  }
  float inv[4];
  #pragma unroll
  for (int r = 0; r < 4; ++r) inv[r] = 1.0f / lrun[r];
  #pragma unroll
  for (int dt = 0; dt < 4; ++dt)
    #pragma unroll
    for (int r = 0; r < 4; ++r){
      int qg = qrow0 + sub * 4 + r;
      if (qg < N_)
        o[((size_t)b * N_ + qg) * DIM_ + hh * HD_ + dt * 16 + ln] = f2b(oacc[dt][r] * inv[r]);
    }
}

// ---------- workspace layout (bytes, all 256-aligned) ----------
#define OFF_WQKV  0ull
#define OFF_WPROJ 3538944ull
#define OFF_WFC1  4718592ull
#define OFF_WFC2  9437184ull
#define OFF_BUFA  14155776ull                       // h (LN1 out), then attn O
#define OFF_BUFB  (OFF_BUFA + 28360704ull)          // q, then h2 (LN2 out)
#define OFF_BUFC  (OFF_BUFB + 28360704ull)          // k | vt, then h3 (fc1 out)
#define OFF_VT    (OFF_BUFC + 28360704ull)
// total ≈ 130.7 MB

extern "C" void kernel_launch(void* const* d_in, const int* in_sizes, int n_in,
                              void* d_out, int out_size, void* d_ws, size_t ws_size,
                              hipStream_t stream)
{
  const float* x     = (const float*)d_in[0];
  const float* mask  = (const float*)d_in[1];
  const float* ln1g  = (const float*)d_in[2];
  const float* ln1b  = (const float*)d_in[3];
  const float* wqkv  = (const float*)d_in[4];
  const float* wproj = (const float*)d_in[5];
  const float* bproj = (const float*)d_in[6];
  const float* ln2g  = (const float*)d_in[7];
  const float* ln2b  = (const float*)d_in[8];
  const float* wfc1  = (const float*)d_in[9];
  const float* bfc1  = (const float*)d_in[10];
  const float* wfc2  = (const float*)d_in[11];
  const float* bfc2  = (const float*)d_in[12];
  float* out = (float*)d_out;

  char* ws = (char*)d_ws;
  u16* wqkv_t  = (u16*)(ws + OFF_WQKV);
  u16* wproj_t = (u16*)(ws + OFF_WPROJ);
  u16* wfc1_t  = (u16*)(ws + OFF_WFC1);
  u16* wfc2_t  = (u16*)(ws + OFF_WFC2);
  u16* hbuf  = (u16*)(ws + OFF_BUFA);   // LN1 out
  u16* obuf  = (u16*)(ws + OFF_BUFA);   // attn out (reuses h)
  u16* qbuf  = (u16*)(ws + OFF_BUFB);
  u16* h2buf = (u16*)(ws + OFF_BUFB);   // LN2 out (reuses q)
  u16* kbuf  = (u16*)(ws + OFF_BUFC);
  u16* vtbuf = (u16*)(ws + OFF_VT);
  u16* h3buf = (u16*)(ws + OFF_BUFC);   // fc1 out chunk (reuses k|vt)

  dim3 tb(32, 8);
  convT<<<dim3(2304/32, 768/32), tb, 0, stream>>>(wqkv,  wqkv_t,  768,  2304);
  convT<<<dim3(768/32,  768/32), tb, 0, stream>>>(wproj, wproj_t, 768,  768);
  convT<<<dim3(3072/32, 768/32), tb, 0, stream>>>(wfc1,  wfc1_t,  768,  3072);
  convT<<<dim3(768/32, 3072/32), tb, 0, stream>>>(wfc2,  wfc2_t,  3072, 768);

  ln_k<<<MTOT_, 256, 0, stream>>>(x, ln1g, ln1b, hbuf);

  // QKV: [18464,768] x [768,2304]
  gemm_bt<0><<<dim3(145, 18), 256, 0, stream>>>(hbuf, wqkv_t, MTOT_, 2304, 768,
      nullptr, nullptr, nullptr, nullptr, qbuf, kbuf, vtbuf);

  attn_k<<<dim3(10, 384), 256, 0, stream>>>(qbuf, kbuf, vtbuf, mask, obuf);

  // proj + bias + residual(x) -> d_out (fp32)
  gemm_bt<1><<<dim3(145, 6), 256, 0, stream>>>(obuf, wproj_t, MTOT_, 768, 768,
      bproj, x, out, nullptr, nullptr, nullptr, nullptr);

  ln_k<<<MTOT_, 256, 0, stream>>>(out, ln2g, ln2b, h2buf);

  // MLP in two row-chunks so h3 fits the dead k|vt region
  const int M0 = 9216, M1 = MTOT_ - M0;  // 9216 + 9248
  // chunk 0
  gemm_bt<2><<<dim3(72, 24), 256, 0, stream>>>(h2buf, wfc1_t, M0, 3072, 768,
      bfc1, nullptr, nullptr, h3buf, nullptr, nullptr, nullptr);
  gemm_bt<1><<<dim3(72, 6), 256, 0, stream>>>(h3buf, wfc2_t, M0, 768, 3072,
      bfc2, out, out, nullptr, nullptr, nullptr, nullptr);
  // chunk 1
  gemm_bt<2><<<dim3(73, 24), 256, 0, stream>>>(h2buf + (size_t)M0 * 768, wfc1_t, M1, 3072, 768,
      bfc1, nullptr, nullptr, h3buf, nullptr, nullptr, nullptr);
  gemm_bt<1><<<dim3(73, 6), 256, 0, stream>>>(h3buf, wfc2_t, M1, 768, 3072,
      bfc2, out + (size_t)M0 * 768, out + (size_t)M0 * 768, nullptr, nullptr, nullptr, nullptr);
}

// Round 3
// 980.185 us; speedup vs baseline: 1.1330x; 1.1330x over previous
//
#include <hip/hip_runtime.h>
#include <math.h>

typedef unsigned short u16;
typedef unsigned int u32;
typedef __attribute__((ext_vector_type(8))) short bf16x8;   // 8 bf16 in 4 VGPRs
typedef __attribute__((ext_vector_type(4))) float f32x4;

#define B_    32
#define N_    577
#define DIM_  768
#define HEADS_ 12
#define HD_   64
#define HID_  3072
#define MTOT_ (B_*N_)      // 18464
#define NP_   640          // padded key-length for v^T rows

// ---------- bf16 helpers (RNE) ----------
__device__ __forceinline__ u16 f2b(float f){
  u32 u = __builtin_bit_cast(u32, f);
  u += 0x7fffu + ((u >> 16) & 1u);
  return (u16)(u >> 16);
}
__device__ __forceinline__ float b2f(u16 h){
  return __builtin_bit_cast(float, (u32)h << 16);
}

// ---------- async global->LDS (wave-uniform base + lane*size dest) ----------
__device__ __forceinline__ void gl_lds16(const void* g, void* l){
  __builtin_amdgcn_global_load_lds(
      (const __attribute__((address_space(1))) u32*)g,
      (__attribute__((address_space(3))) u32*)l, 16, 0, 0);
}
__device__ __forceinline__ void gl_lds4(const void* g, void* l){
  __builtin_amdgcn_global_load_lds(
      (const __attribute__((address_space(1))) u32*)g,
      (__attribute__((address_space(3))) u32*)l, 4, 0, 0);
}

// ---------- weight convert + transpose: w[K][N] fp32 -> wt[N][K] bf16 ----------
__global__ __launch_bounds__(256) void convT(const float* __restrict__ w,
                                             u16* __restrict__ wt, int K, int N){
  __shared__ float t[32][33];
  int n0 = blockIdx.x * 32, k0 = blockIdx.y * 32;
  int tx = threadIdx.x, ty = threadIdx.y;     // block (32,8)
  #pragma unroll
  for (int j = 0; j < 4; ++j)
    t[ty + j*8][tx] = w[(size_t)(k0 + ty + j*8) * N + n0 + tx];
  __syncthreads();
  #pragma unroll
  for (int j = 0; j < 4; ++j)
    wt[(size_t)(n0 + ty + j*8) * K + k0 + tx] = f2b(t[tx][ty + j*8]);
}

// ---------- LayerNorm row kernel: fp32 in -> bf16 out ----------
__global__ __launch_bounds__(256) void ln_k(const float* __restrict__ x,
                                            const float* __restrict__ g,
                                            const float* __restrict__ b,
                                            u16* __restrict__ out){
  int row = blockIdx.x, tid = threadIdx.x;
  const float* xr = x + (size_t)row * DIM_;
  float v0 = xr[tid], v1 = xr[tid + 256], v2 = xr[tid + 512];
  float s = v0 + v1 + v2;
  float s2 = v0*v0 + v1*v1 + v2*v2;
  #pragma unroll
  for (int m = 1; m < 64; m <<= 1){ s += __shfl_xor(s, m); s2 += __shfl_xor(s2, m); }
  __shared__ float ws[8];
  int wid = tid >> 6, ln = tid & 63;
  if (ln == 0){ ws[wid] = s; ws[4 + wid] = s2; }
  __syncthreads();
  s  = ws[0] + ws[1] + ws[2] + ws[3];
  s2 = ws[4] + ws[5] + ws[6] + ws[7];
  float mu = s * (1.0f / DIM_);
  float var = s2 * (1.0f / DIM_) - mu * mu;
  float rs = rsqrtf(var + 1e-5f);
  u16* orow = out + (size_t)row * DIM_;
  orow[tid]       = f2b((v0 - mu) * rs * g[tid]       + b[tid]);
  orow[tid + 256] = f2b((v1 - mu) * rs * g[tid + 256] + b[tid + 256]);
  orow[tid + 512] = f2b((v2 - mu) * rs * g[tid + 512] + b[tid + 512]);
}

// ---------- bt-GEMM with async LDS staging ----------
// EPI 0: QKV scatter | EPI 1: fp32 out = acc + bias + resid | EPI 2: bf16 out = gelu(acc+bias)
#define BM 128
#define BN 128
#define BK 32

template<int EPI>
__global__ __launch_bounds__(256) void gemm_bt(
    const u16* __restrict__ A, const u16* __restrict__ Bt,
    int M, int N, int K,
    const float* __restrict__ bias,
    const float* __restrict__ resid,
    float* __restrict__ outf,
    u16* __restrict__ outb,
    u16* __restrict__ qb, u16* __restrict__ kb, u16* __restrict__ vtb)
{
  __shared__ u16 Al[BM * BK];
  __shared__ u16 Bl[BN * BK];
  int tid = threadIdx.x;
  int wid = tid >> 6, l = tid & 63, ln = l & 15, sub = l >> 4;
  int wm = wid >> 1, wn = wid & 1;
  int tm = blockIdx.x, tn = blockIdx.y;

  f32x4 acc[4][4] = {};
  int arow = tid >> 2;            // 0..63
  int acol = (tid & 3) * 8;       // 0,8,16,24

  // per-thread staging bases (lane-linear LDS: byte = tid*16 (+ i*4096))
  int gr0 = tm * BM + arow;      if (gr0 >= M) gr0 = M - 1;
  int gr1 = tm * BM + arow + 64; if (gr1 >= M) gr1 = M - 1;
  const u16* ga0 = A + (size_t)gr0 * K + acol;
  const u16* ga1 = A + (size_t)gr1 * K + acol;
  const u16* gb0 = Bt + (size_t)(tn * BN + arow) * K + acol;
  const u16* gb1 = Bt + (size_t)(tn * BN + arow + 64) * K + acol;
  u16* la0 = &Al[arow * BK + acol];
  u16* la1 = &Al[(arow + 64) * BK + acol];
  u16* lb0 = &Bl[arow * BK + acol];
  u16* lb1 = &Bl[(arow + 64) * BK + acol];

  const int ktiles = K / BK;
  for (int kt = 0; kt < ktiles; ++kt){
    int kbase = kt * BK;
    gl_lds16(ga0 + kbase, la0);
    gl_lds16(ga1 + kbase, la1);
    gl_lds16(gb0 + kbase, lb0);
    gl_lds16(gb1 + kbase, lb1);
    __syncthreads();
    bf16x8 af[4], bfr[4];
    #pragma unroll
    for (int mi = 0; mi < 4; ++mi) af[mi]  = *(const bf16x8*)&Al[(wm*64 + mi*16 + ln) * BK + sub*8];
    #pragma unroll
    for (int ni = 0; ni < 4; ++ni) bfr[ni] = *(const bf16x8*)&Bl[(wn*64 + ni*16 + ln) * BK + sub*8];
    #pragma unroll
    for (int mi = 0; mi < 4; ++mi)
      #pragma unroll
      for (int ni = 0; ni < 4; ++ni)
        acc[mi][ni] = __builtin_amdgcn_mfma_f32_16x16x32_bf16(af[mi], bfr[ni], acc[mi][ni], 0, 0, 0);
    __syncthreads();
  }

  #pragma unroll
  for (int mi = 0; mi < 4; ++mi){
    int rbase = tm * BM + wm * 64 + mi * 16 + sub * 4;
    #pragma unroll
    for (int ni = 0; ni < 4; ++ni){
      int col = tn * BN + wn * 64 + ni * 16 + ln;
      #pragma unroll
      for (int r = 0; r < 4; ++r){
        int grow = rbase + r;
        if (grow >= M) continue;
        float val = acc[mi][ni][r];
        if (EPI == 0){
          u32 bb = (u32)grow / 577u;
          u32 nn = (u32)grow - bb * 577u;
          int which = col / 768;           // 0=q, 1=k, 2=v
          int rem = col - which * 768;     // col % 768 (768 not pow2!)
          int hh = rem >> 6;
          int d  = col & 63;               // ok: 768 % 64 == 0
          if (which == 0)
            qb[(((size_t)bb * HEADS_ + hh) * N_ + nn) * HD_ + d] = f2b(val);
          else if (which == 1)
            kb[(((size_t)bb * HEADS_ + hh) * N_ + nn) * HD_ + d] = f2b(val);
          else
            vtb[(((size_t)bb * HEADS_ + hh) * HD_ + d) * NP_ + nn] = f2b(val);
        } else if (EPI == 1){
          outf[(size_t)grow * N + col] = val + bias[col] + resid[(size_t)grow * N + col];
        } else {
          float t = val + bias[col];
          float ge = 0.5f * t * (1.0f + erff(t * 0.70710678118654752f));
          outb[(size_t)grow * N + col] = f2b(ge);
        }
      }
    }
  }
}

// ---------- fused flash attention with LDS-staged K/V/mask ----------
// grid: x = q-tile (10), y = b*h (384). 4 waves, each owns 16 q-rows.
// K/V tiles stored 64x64 bf16 (128B rows) with chunk-XOR swizzle:
//   physical chunk = logical chunk ^ (row & 7)   (chunk = 16B = 8 bf16)
// Staging writes lane-linear LDS, so the GLOBAL source column is pre-swizzled.
__global__ __launch_bounds__(256) void attn_k(
    const u16* __restrict__ q, const u16* __restrict__ k,
    const u16* __restrict__ vt, const float* __restrict__ mask,
    u16* __restrict__ o)
{
  const float SCALE = 0.125f;
  int qt = blockIdx.x, bh = blockIdx.y;
  int tid = threadIdx.x;
  int wid = tid >> 6, l = tid & 63, ln = l & 15, sub = l >> 4;
  int b = bh / HEADS_, hh = bh - b * HEADS_;
  int qrow0_blk = qt * 64;
  int qrow0 = qrow0_blk + wid * 16;

  __shared__ u16 Kl[64 * 64];     // [kr][d], swizzled, 8KB
  __shared__ u16 Vl[64 * 64];     // [d][kv], swizzled, 8KB
  __shared__ float Ml[64 * 64];   // mask [q][kv], linear, 16KB
  __shared__ u16 Pl[4][16 * 64];  // per-wave P, swizzled, 8KB

  int qr = qrow0 + ln; if (qr > N_ - 1) qr = N_ - 1;
  const u16* qbase = q + ((size_t)bh * N_ + qr) * HD_;
  bf16x8 qf0 = *(const bf16x8*)&qbase[sub * 8];
  bf16x8 qf1 = *(const bf16x8*)&qbase[32 + sub * 8];

  f32x4 oacc[4] = {};
  float mrun[4] = {-1e30f, -1e30f, -1e30f, -1e30f};
  float lrun[4] = {0.f, 0.f, 0.f, 0.f};

  for (int mt = 0; mt < 10; ++mt){
    int mbase = mt * 64;
    // ---- stage K, V (pre-swizzled source), mask ----
    #pragma unroll
    for (int p = 0; p < 2; ++p){
      int row = (tid >> 3) + p * 32;
      int sc = (tid & 7) ^ (row & 7);            // pre-swizzled source chunk
      int kr = mbase + row; if (kr > N_ - 1) kr = N_ - 1;
      gl_lds16(&k[((size_t)bh * N_ + kr) * HD_ + sc * 8], &Kl[row * 64 + (tid & 7) * 8]);
      gl_lds16(&vt[((size_t)bh * HD_ + row) * NP_ + mbase + sc * 8], &Vl[row * 64 + (tid & 7) * 8]);
    }
    if (mbase + 63 < N_){
      #pragma unroll
      for (int p = 0; p < 4; ++p){
        int row = (tid >> 4) + p * 16;
        int grow = qrow0_blk + row; if (grow > N_ - 1) grow = N_ - 1;
        gl_lds16(&mask[(size_t)grow * N_ + mbase + (tid & 15) * 4], &Ml[row * 64 + (tid & 15) * 4]);
      }
    } else {
      // ragged last tile: 4B staging with col clamp (values for col>=N_ are
      // overridden to -1e30 below, only col N_-1 must be exact)
      #pragma unroll
      for (int p = 0; p < 16; ++p){
        int row = (tid >> 6) + p * 4;
        int grow = qrow0_blk + row; if (grow > N_ - 1) grow = N_ - 1;
        int gcol = mbase + (tid & 63); if (gcol > N_ - 1) gcol = N_ - 1;
        gl_lds4(&mask[(size_t)grow * N_ + gcol], &Ml[row * 64 + (tid & 63)]);
      }
    }
    __syncthreads();

    // ---- QK^T from LDS ----
    f32x4 s[4];
    #pragma unroll
    for (int c = 0; c < 4; ++c){
      int krow = c * 16 + ln;
      bf16x8 kf0 = *(const bf16x8*)&Kl[krow * 64 + ((sub    ) ^ (krow & 7)) * 8];
      bf16x8 kf1 = *(const bf16x8*)&Kl[krow * 64 + ((4 + sub) ^ (krow & 7)) * 8];
      f32x4 z = {};
      z = __builtin_amdgcn_mfma_f32_16x16x32_bf16(qf0, kf0, z, 0, 0, 0);
      z = __builtin_amdgcn_mfma_f32_16x16x32_bf16(qf1, kf1, z, 0, 0, 0);
      s[c] = z;
    }
    // ---- scale * mask (from LDS) ----
    #pragma unroll
    for (int c = 0; c < 4; ++c){
      int mg = mbase + c * 16 + ln;
      #pragma unroll
      for (int r = 0; r < 4; ++r){
        if (mg < N_)
          s[c][r] = s[c][r] * SCALE * Ml[(sub * 4 + r) * 64 + c * 16 + ln];
        else
          s[c][r] = -1e30f;
      }
    }
    // ---- online softmax (rows live across 16-lane groups) ----
    float pm[4];
    #pragma unroll
    for (int r = 0; r < 4; ++r)
      pm[r] = fmaxf(fmaxf(s[0][r], s[1][r]), fmaxf(s[2][r], s[3][r]));
    #pragma unroll
    for (int m = 1; m < 16; m <<= 1){
      #pragma unroll
      for (int r = 0; r < 4; ++r) pm[r] = fmaxf(pm[r], __shfl_xor(pm[r], m));
    }
    float alpha[4];
    #pragma unroll
    for (int r = 0; r < 4; ++r){
      float mnew = fmaxf(mrun[r], pm[r]);
      alpha[r] = __expf(mrun[r] - mnew);
      mrun[r] = mnew;
    }
    float ps[4] = {0.f, 0.f, 0.f, 0.f};
    #pragma unroll
    for (int c = 0; c < 4; ++c)
      #pragma unroll
      for (int r = 0; r < 4; ++r){
        float p = __expf(s[c][r] - mrun[r]);
        s[c][r] = p;
        ps[r] += p;
      }
    #pragma unroll
    for (int m = 1; m < 16; m <<= 1){
      #pragma unroll
      for (int r = 0; r < 4; ++r) ps[r] += __shfl_xor(ps[r], m);
    }
    #pragma unroll
    for (int r = 0; r < 4; ++r) lrun[r] = lrun[r] * alpha[r] + ps[r];
    // ---- P -> per-wave LDS (swizzled) ----
    #pragma unroll
    for (int c = 0; c < 4; ++c)
      #pragma unroll
      for (int r = 0; r < 4; ++r){
        int prow = sub * 4 + r;
        int pcol = c * 16 + ln;
        Pl[wid][prow * 64 + (((pcol >> 3) ^ (prow & 7)) << 3) + (pcol & 7)] = f2b(s[c][r]);
      }
    // ---- rescale O ----
    #pragma unroll
    for (int dt = 0; dt < 4; ++dt)
      #pragma unroll
      for (int r = 0; r < 4; ++r) oacc[dt][r] *= alpha[r];
    // ---- PV from LDS ----
    #pragma unroll
    for (int half = 0; half < 2; ++half){
      bf16x8 pa = *(const bf16x8*)&Pl[wid][ln * 64 + (((half * 4 + sub) ^ (ln & 7)) << 3)];
      #pragma unroll
      for (int dt = 0; dt < 4; ++dt){
        int vrow = dt * 16 + ln;
        bf16x8 vf = *(const bf16x8*)&Vl[vrow * 64 + (((half * 4 + sub) ^ (vrow & 7)) << 3)];
        oacc[dt] = __builtin_amdgcn_mfma_f32_16x16x32_bf16(pa, vf, oacc[dt], 0, 0, 0);
      }
    }
    __syncthreads();   // all waves done with Kl/Vl/Ml before next stage
  }
  float inv[4];
  #pragma unroll
  for (int r = 0; r < 4; ++r) inv[r] = 1.0f / lrun[r];
  #pragma unroll
  for (int dt = 0; dt < 4; ++dt)
    #pragma unroll
    for (int r = 0; r < 4; ++r){
      int qg = qrow0 + sub * 4 + r;
      if (qg < N_)
        o[((size_t)b * N_ + qg) * DIM_ + hh * HD_ + dt * 16 + ln] = f2b(oacc[dt][r] * inv[r]);
    }
}

// ---------- workspace layout (bytes, all 256-aligned) ----------
#define OFF_WQKV  0ull
#define OFF_WPROJ 3538944ull
#define OFF_WFC1  4718592ull
#define OFF_WFC2  9437184ull
#define OFF_BUFA  14155776ull                       // h (LN1 out), then attn O
#define OFF_BUFB  (OFF_BUFA + 28360704ull)          // q, then h2 (LN2 out)
#define OFF_BUFC  (OFF_BUFB + 28360704ull)          // k | vt, then h3 (fc1 out)
#define OFF_VT    (OFF_BUFC + 28360704ull)
// total ≈ 130.7 MB

extern "C" void kernel_launch(void* const* d_in, const int* in_sizes, int n_in,
                              void* d_out, int out_size, void* d_ws, size_t ws_size,
                              hipStream_t stream)
{
  const float* x     = (const float*)d_in[0];
  const float* mask  = (const float*)d_in[1];
  const float* ln1g  = (const float*)d_in[2];
  const float* ln1b  = (const float*)d_in[3];
  const float* wqkv  = (const float*)d_in[4];
  const float* wproj = (const float*)d_in[5];
  const float* bproj = (const float*)d_in[6];
  const float* ln2g  = (const float*)d_in[7];
  const float* ln2b  = (const float*)d_in[8];
  const float* wfc1  = (const float*)d_in[9];
  const float* bfc1  = (const float*)d_in[10];
  const float* wfc2  = (const float*)d_in[11];
  const float* bfc2  = (const float*)d_in[12];
  float* out = (float*)d_out;

  char* ws = (char*)d_ws;
  u16* wqkv_t  = (u16*)(ws + OFF_WQKV);
  u16* wproj_t = (u16*)(ws + OFF_WPROJ);
  u16* wfc1_t  = (u16*)(ws + OFF_WFC1);
  u16* wfc2_t  = (u16*)(ws + OFF_WFC2);
  u16* hbuf  = (u16*)(ws + OFF_BUFA);   // LN1 out
  u16* obuf  = (u16*)(ws + OFF_BUFA);   // attn out (reuses h)
  u16* qbuf  = (u16*)(ws + OFF_BUFB);
  u16* h2buf = (u16*)(ws + OFF_BUFB);   // LN2 out (reuses q)
  u16* kbuf  = (u16*)(ws + OFF_BUFC);
  u16* vtbuf = (u16*)(ws + OFF_VT);
  u16* h3buf = (u16*)(ws + OFF_BUFC);   // fc1 out chunk (reuses k|vt)

  dim3 tb(32, 8);
  convT<<<dim3(2304/32, 768/32), tb, 0, stream>>>(wqkv,  wqkv_t,  768,  2304);
  convT<<<dim3(768/32,  768/32), tb, 0, stream>>>(wproj, wproj_t, 768,  768);
  convT<<<dim3(3072/32, 768/32), tb, 0, stream>>>(wfc1,  wfc1_t,  768,  3072);
  convT<<<dim3(768/32, 3072/32), tb, 0, stream>>>(wfc2,  wfc2_t,  3072, 768);

  ln_k<<<MTOT_, 256, 0, stream>>>(x, ln1g, ln1b, hbuf);

  // QKV: [18464,768] x [768,2304]
  gemm_bt<0><<<dim3(145, 18), 256, 0, stream>>>(hbuf, wqkv_t, MTOT_, 2304, 768,
      nullptr, nullptr, nullptr, nullptr, qbuf, kbuf, vtbuf);

  attn_k<<<dim3(10, 384), 256, 0, stream>>>(qbuf, kbuf, vtbuf, mask, obuf);

  // proj + bias + residual(x) -> d_out (fp32)
  gemm_bt<1><<<dim3(145, 6), 256, 0, stream>>>(obuf, wproj_t, MTOT_, 768, 768,
      bproj, x, out, nullptr, nullptr, nullptr, nullptr);

  ln_k<<<MTOT_, 256, 0, stream>>>(out, ln2g, ln2b, h2buf);

  // MLP in two row-chunks so h3 fits the dead k|vt region
  const int M0 = 9216, M1 = MTOT_ - M0;  // 9216 + 9248
  // chunk 0
  gemm_bt<2><<<dim3(72, 24), 256, 0, stream>>>(h2buf, wfc1_t, M0, 3072, 768,
      bfc1, nullptr, nullptr, h3buf, nullptr, nullptr, nullptr);
  gemm_bt<1><<<dim3(72, 6), 256, 0, stream>>>(h3buf, wfc2_t, M0, 768, 3072,
      bfc2, out, out, nullptr, nullptr, nullptr, nullptr);
  // chunk 1
  gemm_bt<2><<<dim3(73, 24), 256, 0, stream>>>(h2buf + (size_t)M0 * 768, wfc1_t, M1, 3072, 768,
      bfc1, nullptr, nullptr, h3buf, nullptr, nullptr, nullptr);
  gemm_bt<1><<<dim3(73, 6), 256, 0, stream>>>(h3buf, wfc2_t, M1, 768, 3072,
      bfc2, out + (size_t)M0 * 768, out + (size_t)M0 * 768, nullptr, nullptr, nullptr, nullptr);
}

// Round 6
// 908.008 us; speedup vs baseline: 1.2230x; 1.0795x over previous
//
#include <hip/hip_runtime.h>
#include <math.h>

typedef unsigned short u16;
typedef unsigned int u32;
typedef __attribute__((ext_vector_type(8))) short bf16x8;   // 8 bf16 in 4 VGPRs
typedef __attribute__((ext_vector_type(4))) float f32x4;

#define B_    32
#define N_    577
#define DIM_  768
#define HEADS_ 12
#define HD_   64
#define HID_  3072
#define MTOT_ (B_*N_)      // 18464
#define NP_   640          // padded key-length for v^T rows

// ---------- bf16 helpers (RNE) ----------
__device__ __forceinline__ u16 f2b(float f){
  u32 u = __builtin_bit_cast(u32, f);
  u += 0x7fffu + ((u >> 16) & 1u);
  return (u16)(u >> 16);
}
// pack two f32 -> two bf16 in one u32 (lo = first arg)
__device__ __forceinline__ u32 cvtpk(float lo, float hi){
  u32 r;
  asm("v_cvt_pk_bf16_f32 %0, %1, %2" : "=v"(r) : "v"(lo), "v"(hi));
  return r;
}

// ---------- async global->LDS (dest must be linear in tid: base + tid*size) ----------
__device__ __forceinline__ void gl_lds16(const void* g, void* l){
  __builtin_amdgcn_global_load_lds(
      (const __attribute__((address_space(1))) u32*)g,
      (__attribute__((address_space(3))) u32*)l, 16, 0, 0);
}
__device__ __forceinline__ void gl_lds4(const void* g, void* l){
  __builtin_amdgcn_global_load_lds(
      (const __attribute__((address_space(1))) u32*)g,
      (__attribute__((address_space(3))) u32*)l, 4, 0, 0);
}

// ---------- weight convert + transpose: w[K][N] fp32 -> wt[N][K] bf16 ----------
__global__ __launch_bounds__(256) void convT(const float* __restrict__ w,
                                             u16* __restrict__ wt, int K, int N){
  __shared__ float t[32][33];
  int n0 = blockIdx.x * 32, k0 = blockIdx.y * 32;
  int tx = threadIdx.x, ty = threadIdx.y;     // block (32,8)
  #pragma unroll
  for (int j = 0; j < 4; ++j)
    t[ty + j*8][tx] = w[(size_t)(k0 + ty + j*8) * N + n0 + tx];
  __syncthreads();
  #pragma unroll
  for (int j = 0; j < 4; ++j)
    wt[(size_t)(n0 + ty + j*8) * K + k0 + tx] = f2b(t[tx][ty + j*8]);
}

// ---------- LayerNorm row kernel: fp32 in -> bf16 out ----------
__global__ __launch_bounds__(256) void ln_k(const float* __restrict__ x,
                                            const float* __restrict__ g,
                                            const float* __restrict__ b,
                                            u16* __restrict__ out){
  int row = blockIdx.x, tid = threadIdx.x;
  const float* xr = x + (size_t)row * DIM_;
  float v0 = xr[tid], v1 = xr[tid + 256], v2 = xr[tid + 512];
  float s = v0 + v1 + v2;
  float s2 = v0*v0 + v1*v1 + v2*v2;
  #pragma unroll
  for (int m = 1; m < 64; m <<= 1){ s += __shfl_xor(s, m); s2 += __shfl_xor(s2, m); }
  __shared__ float ws[8];
  int wid = tid >> 6, ln = tid & 63;
  if (ln == 0){ ws[wid] = s; ws[4 + wid] = s2; }
  __syncthreads();
  s  = ws[0] + ws[1] + ws[2] + ws[3];
  s2 = ws[4] + ws[5] + ws[6] + ws[7];
  float mu = s * (1.0f / DIM_);
  float var = s2 * (1.0f / DIM_) - mu * mu;
  float rs = rsqrtf(var + 1e-5f);
  u16* orow = out + (size_t)row * DIM_;
  orow[tid]       = f2b((v0 - mu) * rs * g[tid]       + b[tid]);
  orow[tid + 256] = f2b((v1 - mu) * rs * g[tid + 256] + b[tid + 256]);
  orow[tid + 512] = f2b((v2 - mu) * rs * g[tid + 512] + b[tid + 512]);
}

// ---------- bt-GEMM with async LDS staging + bijective XCD swizzle ----------
// EPI 0: QKV scatter | EPI 1: fp32 out = acc + bias + resid | EPI 2: bf16 out = gelu(acc+bias)
#define BM 128
#define BN 128
#define BK 32

template<int EPI>
__global__ __launch_bounds__(256) void gemm_bt(
    const u16* __restrict__ A, const u16* __restrict__ Bt,
    int M, int N, int K,
    const float* __restrict__ bias,
    const float* __restrict__ resid,
    float* __restrict__ outf,
    u16* __restrict__ outb,
    u16* __restrict__ qb, u16* __restrict__ kb, u16* __restrict__ vtb)
{
  __shared__ u16 Al[BM * BK];
  __shared__ u16 Bl[BN * BK];
  int tid = threadIdx.x;
  int wid = tid >> 6, l = tid & 63, ln = l & 15, sub = l >> 4;
  int wm = wid >> 1, wn = wid & 1;

  // bijective XCD swizzle (m204): contiguous tm-major chunks per XCD
  // so each XCD reuses a small set of A-row panels from its own L2.
  int nwg  = gridDim.x * gridDim.y;
  int flat = blockIdx.x + gridDim.x * blockIdx.y;
  int q8 = nwg >> 3, r8 = nwg & 7;
  int xcd = flat & 7, j8 = flat >> 3;
  int wgid = (xcd < r8 ? xcd * (q8 + 1) : r8 * (q8 + 1) + (xcd - r8) * q8) + j8;
  int tm = wgid / gridDim.y;
  int tn = wgid - tm * gridDim.y;

  f32x4 acc[4][4] = {};
  int arow = tid >> 2;            // 0..63
  int acol = (tid & 3) * 8;       // 0,8,16,24

  int gr0 = tm * BM + arow;      if (gr0 >= M) gr0 = M - 1;
  int gr1 = tm * BM + arow + 64; if (gr1 >= M) gr1 = M - 1;
  const u16* ga0 = A + (size_t)gr0 * K + acol;
  const u16* ga1 = A + (size_t)gr1 * K + acol;
  const u16* gb0 = Bt + (size_t)(tn * BN + arow) * K + acol;
  const u16* gb1 = Bt + (size_t)(tn * BN + arow + 64) * K + acol;
  u16* la0 = &Al[arow * BK + acol];
  u16* la1 = &Al[(arow + 64) * BK + acol];
  u16* lb0 = &Bl[arow * BK + acol];
  u16* lb1 = &Bl[(arow + 64) * BK + acol];

  const int ktiles = K / BK;
  for (int kt = 0; kt < ktiles; ++kt){
    int kbase = kt * BK;
    gl_lds16(ga0 + kbase, la0);
    gl_lds16(ga1 + kbase, la1);
    gl_lds16(gb0 + kbase, lb0);
    gl_lds16(gb1 + kbase, lb1);
    __syncthreads();
    bf16x8 af[4], bfr[4];
    #pragma unroll
    for (int mi = 0; mi < 4; ++mi) af[mi]  = *(const bf16x8*)&Al[(wm*64 + mi*16 + ln) * BK + sub*8];
    #pragma unroll
    for (int ni = 0; ni < 4; ++ni) bfr[ni] = *(const bf16x8*)&Bl[(wn*64 + ni*16 + ln) * BK + sub*8];
    #pragma unroll
    for (int mi = 0; mi < 4; ++mi)
      #pragma unroll
      for (int ni = 0; ni < 4; ++ni)
        acc[mi][ni] = __builtin_amdgcn_mfma_f32_16x16x32_bf16(af[mi], bfr[ni], acc[mi][ni], 0, 0, 0);
    __syncthreads();
  }

  #pragma unroll
  for (int mi = 0; mi < 4; ++mi){
    int rbase = tm * BM + wm * 64 + mi * 16 + sub * 4;
    #pragma unroll
    for (int ni = 0; ni < 4; ++ni){
      int col = tn * BN + wn * 64 + ni * 16 + ln;
      #pragma unroll
      for (int r = 0; r < 4; ++r){
        int grow = rbase + r;
        if (grow >= M) continue;
        float val = acc[mi][ni][r];
        if (EPI == 0){
          u32 bb = (u32)grow / 577u;
          u32 nn = (u32)grow - bb * 577u;
          int which = col / 768;           // 0=q, 1=k, 2=v
          int rem = col - which * 768;     // col % 768 (768 not pow2!)
          int hh = rem >> 6;
          int d  = col & 63;               // ok: 768 % 64 == 0
          if (which == 0)
            qb[(((size_t)bb * HEADS_ + hh) * N_ + nn) * HD_ + d] = f2b(val);
          else if (which == 1)
            kb[(((size_t)bb * HEADS_ + hh) * N_ + nn) * HD_ + d] = f2b(val);
          else
            vtb[(((size_t)bb * HEADS_ + hh) * HD_ + d) * NP_ + nn] = f2b(val);
        } else if (EPI == 1){
          outf[(size_t)grow * N + col] = val + bias[col] + resid[(size_t)grow * N + col];
        } else {
          float t = val + bias[col];
          float ge = 0.5f * t * (1.0f + erff(t * 0.70710678118654752f));
          outb[(size_t)grow * N + col] = f2b(ge);
        }
      }
    }
  }
}

// ---------- fused flash attention, swapped-QK^T layout ----------
// grid: x = b*h (384) -> flat%8 = bh%8, all q-tiles of a bh share an XCD L2.
//       y = q-tile (10). 4 waves, each owns 16 q-rows; each LANE owns 1 q-row.
// Swapped mfma(K,Q): S^T layout -> lane(ln,sub) holds S[k=c*16+sub*4+r][q=ln].
// Softmax reduce = 2 shfl_xor (x16, x32) on scalars. P packed via cvt_pk into
// per-wave LDS (row = q = ln), read back as A-frag for PV.
__global__ __launch_bounds__(256) void attn_k(
    const u16* __restrict__ q, const u16* __restrict__ k,
    const u16* __restrict__ vt, const float* __restrict__ mask,
    u16* __restrict__ o)
{
  const float SCALE = 0.125f;
  int bh = blockIdx.x, qt = blockIdx.y;
  int tid = threadIdx.x;
  int wid = tid >> 6, l = tid & 63, ln = l & 15, sub = l >> 4;
  int b = bh / HEADS_, hh = bh - b * HEADS_;
  int qrow0_blk = qt * 64;
  int qrow0 = qrow0_blk + wid * 16;

  __shared__ u16 Kl[64 * 64];     // [kr][d], chunk-XOR swizzled, 8KB
  __shared__ u16 Vl[64 * 64];     // [d][kv], chunk-XOR swizzled, 8KB
  __shared__ float Ml[64 * 64];   // mask [q][kv], fp32-chunk-XOR swizzled, 16KB
  __shared__ u16 Pl[4][16 * 64];  // per-wave P [q=ln][k], chunk-XOR swizzled, 8KB

  int qr = qrow0 + ln; if (qr > N_ - 1) qr = N_ - 1;
  const u16* qbase = q + ((size_t)bh * N_ + qr) * HD_;
  bf16x8 qf0 = *(const bf16x8*)&qbase[sub * 8];        // B-frag: Q[q=ln][d=sub*8+j]
  bf16x8 qf1 = *(const bf16x8*)&qbase[32 + sub * 8];

  f32x4 oacc[4] = {};
  float mrun = -1e30f, lrun = 0.f;

  for (int mt = 0; mt < 10; ++mt){
    int mbase = mt * 64;
    // ---- stage K, V (pre-swizzled source, 16B chunk ^ row&7) ----
    #pragma unroll
    for (int p = 0; p < 2; ++p){
      int row = (tid >> 3) + p * 32;
      int sc = (tid & 7) ^ (row & 7);
      int kr = mbase + row; if (kr > N_ - 1) kr = N_ - 1;
      gl_lds16(&k[((size_t)bh * N_ + kr) * HD_ + sc * 8], &Kl[row * 64 + (tid & 7) * 8]);
      gl_lds16(&vt[((size_t)bh * HD_ + row) * NP_ + mbase + sc * 8], &Vl[row * 64 + (tid & 7) * 8]);
    }
    // ---- stage mask with fp32 chunk-XOR swizzle: phys chunk = logical ^ (row&15) ----
    if (mbase + 63 < N_){
      #pragma unroll
      for (int p = 0; p < 4; ++p){
        int row = (tid >> 4) + p * 16;
        int grow = qrow0_blk + row; if (grow > N_ - 1) grow = N_ - 1;
        int sc = (tid & 15) ^ (row & 15);           // pre-swizzled source chunk (4 floats)
        gl_lds16(&mask[(size_t)grow * N_ + mbase + sc * 4], &Ml[row * 64 + (tid & 15) * 4]);
      }
    } else {
      // ragged last tile: per-float staging; value at phys (row,kp) comes from
      // logical col ((kp>>2)^(row&15))*4 + (kp&3), clamped
      #pragma unroll
      for (int p = 0; p < 16; ++p){
        int row = (tid >> 6) + p * 4;
        int grow = qrow0_blk + row; if (grow > N_ - 1) grow = N_ - 1;
        int kp = tid & 63;
        int lcol = ((((kp >> 2) ^ (row & 15)) << 2) | (kp & 3));
        int gcol = mbase + lcol; if (gcol > N_ - 1) gcol = N_ - 1;
        gl_lds4(&mask[(size_t)grow * N_ + gcol], &Ml[row * 64 + kp]);
      }
    }
    __syncthreads();

    // ---- QK^T (swapped): s[c] lane(ln,sub) reg r = S[k=c*16+sub*4+r][q=ln] ----
    f32x4 s[4];
    #pragma unroll
    for (int c = 0; c < 4; ++c){
      int krow = c * 16 + ln;
      bf16x8 kf0 = *(const bf16x8*)&Kl[krow * 64 + ((sub    ) ^ (krow & 7)) * 8];
      bf16x8 kf1 = *(const bf16x8*)&Kl[krow * 64 + ((4 + sub) ^ (krow & 7)) * 8];
      f32x4 z = {};
      z = __builtin_amdgcn_mfma_f32_16x16x32_bf16(kf0, qf0, z, 0, 0, 0);
      z = __builtin_amdgcn_mfma_f32_16x16x32_bf16(kf1, qf1, z, 0, 0, 0);
      s[c] = z;
    }
    // ---- scale * mask: lane needs mask[q=ln(row in block)][k=c*16+sub*4+r] ----
    int mrow = wid * 16 + ln;
    #pragma unroll
    for (int c = 0; c < 4; ++c){
      f32x4 mv = *(const f32x4*)&Ml[mrow * 64 + (((c * 4 + sub) ^ ln) << 2)];
      int mg0 = mbase + c * 16 + sub * 4;
      #pragma unroll
      for (int r = 0; r < 4; ++r){
        if (mg0 + r < N_) s[c][r] = s[c][r] * SCALE * mv[r];
        else              s[c][r] = -1e30f;
      }
    }
    // ---- online softmax: row q=ln lives on lanes {ln, ln+16, ln+32, ln+48} ----
    float pm = s[0][0];
    #pragma unroll
    for (int c = 0; c < 4; ++c)
      #pragma unroll
      for (int r = 0; r < 4; ++r) pm = fmaxf(pm, s[c][r]);
    pm = fmaxf(pm, __shfl_xor(pm, 16));
    pm = fmaxf(pm, __shfl_xor(pm, 32));
    float mnew = fmaxf(mrun, pm);
    float alpha = __expf(mrun - mnew);
    mrun = mnew;
    float ps = 0.f;
    #pragma unroll
    for (int c = 0; c < 4; ++c)
      #pragma unroll
      for (int r = 0; r < 4; ++r){
        float p = __expf(s[c][r] - mrun);
        s[c][r] = p;
        ps += p;
      }
    ps += __shfl_xor(ps, 16);
    ps += __shfl_xor(ps, 32);
    lrun = lrun * alpha + ps;
    // ---- P pack (cvt_pk) -> per-wave LDS, row = q = ln, chunk-XOR swizzle ----
    #pragma unroll
    for (int c = 0; c < 4; ++c)
      #pragma unroll
      for (int h = 0; h < 2; ++h){
        int kk = c * 16 + sub * 4 + 2 * h;
        u32 w = cvtpk(s[c][2 * h], s[c][2 * h + 1]);
        *(u32*)&Pl[wid][ln * 64 + (((kk >> 3) ^ (ln & 7)) << 3) + (kk & 7)] = w;
      }
    // ---- rescale O: needs alpha at q-row = sub*4+r (D-layout) ----
    float a_d[4];
    #pragma unroll
    for (int r = 0; r < 4; ++r) a_d[r] = __shfl(alpha, sub * 4 + r);
    #pragma unroll
    for (int dt = 0; dt < 4; ++dt)
      #pragma unroll
      for (int r = 0; r < 4; ++r) oacc[dt][r] *= a_d[r];
    // ---- PV: A = P rows (q=ln), B = Vt rows (d) ----
    #pragma unroll
    for (int kbv = 0; kbv < 2; ++kbv){
      bf16x8 pa = *(const bf16x8*)&Pl[wid][ln * 64 + (((kbv * 4 + sub) ^ (ln & 7)) << 3)];
      #pragma unroll
      for (int dt = 0; dt < 4; ++dt){
        int vrow = dt * 16 + ln;
        bf16x8 vf = *(const bf16x8*)&Vl[vrow * 64 + (((kbv * 4 + sub) ^ (vrow & 7)) << 3)];
        oacc[dt] = __builtin_amdgcn_mfma_f32_16x16x32_bf16(pa, vf, oacc[dt], 0, 0, 0);
      }
    }
    __syncthreads();   // all waves done with Kl/Vl/Ml before next stage
  }
  // ---- epilogue: O[q = qrow0 + sub*4 + r][d = dt*16 + ln] ----
  float rinv = 1.0f / lrun;
  float inv_d[4];
  #pragma unroll
  for (int r = 0; r < 4; ++r) inv_d[r] = __shfl(rinv, sub * 4 + r);
  #pragma unroll
  for (int dt = 0; dt < 4; ++dt)
    #pragma unroll
    for (int r = 0; r < 4; ++r){
      int qg = qrow0 + sub * 4 + r;
      if (qg < N_)
        o[((size_t)b * N_ + qg) * DIM_ + hh * HD_ + dt * 16 + ln] = f2b(oacc[dt][r] * inv_d[r]);
    }
}

// ---------- workspace layout (bytes, all 256-aligned) ----------
#define OFF_WQKV  0ull
#define OFF_WPROJ 3538944ull
#define OFF_WFC1  4718592ull
#define OFF_WFC2  9437184ull
#define OFF_BUFA  14155776ull                       // h (LN1 out), then attn O
#define OFF_BUFB  (OFF_BUFA + 28360704ull)          // q, then h2 (LN2 out)
#define OFF_BUFC  (OFF_BUFB + 28360704ull)          // k | vt, then h3 (fc1 out)
#define OFF_VT    (OFF_BUFC + 28360704ull)
// total ≈ 130.7 MB

extern "C" void kernel_launch(void* const* d_in, const int* in_sizes, int n_in,
                              void* d_out, int out_size, void* d_ws, size_t ws_size,
                              hipStream_t stream)
{
  const float* x     = (const float*)d_in[0];
  const float* mask  = (const float*)d_in[1];
  const float* ln1g  = (const float*)d_in[2];
  const float* ln1b  = (const float*)d_in[3];
  const float* wqkv  = (const float*)d_in[4];
  const float* wproj = (const float*)d_in[5];
  const float* bproj = (const float*)d_in[6];
  const float* ln2g  = (const float*)d_in[7];
  const float* ln2b  = (const float*)d_in[8];
  const float* wfc1  = (const float*)d_in[9];
  const float* bfc1  = (const float*)d_in[10];
  const float* wfc2  = (const float*)d_in[11];
  const float* bfc2  = (const float*)d_in[12];
  float* out = (float*)d_out;

  char* ws = (char*)d_ws;
  u16* wqkv_t  = (u16*)(ws + OFF_WQKV);
  u16* wproj_t = (u16*)(ws + OFF_WPROJ);
  u16* wfc1_t  = (u16*)(ws + OFF_WFC1);
  u16* wfc2_t  = (u16*)(ws + OFF_WFC2);
  u16* hbuf  = (u16*)(ws + OFF_BUFA);   // LN1 out
  u16* obuf  = (u16*)(ws + OFF_BUFA);   // attn out (reuses h)
  u16* qbuf  = (u16*)(ws + OFF_BUFB);
  u16* h2buf = (u16*)(ws + OFF_BUFB);   // LN2 out (reuses q)
  u16* kbuf  = (u16*)(ws + OFF_BUFC);
  u16* vtbuf = (u16*)(ws + OFF_VT);
  u16* h3buf = (u16*)(ws + OFF_BUFC);   // fc1 out chunk (reuses k|vt)

  dim3 tb(32, 8);
  convT<<<dim3(2304/32, 768/32), tb, 0, stream>>>(wqkv,  wqkv_t,  768,  2304);
  convT<<<dim3(768/32,  768/32), tb, 0, stream>>>(wproj, wproj_t, 768,  768);
  convT<<<dim3(3072/32, 768/32), tb, 0, stream>>>(wfc1,  wfc1_t,  768,  3072);
  convT<<<dim3(768/32, 3072/32), tb, 0, stream>>>(wfc2,  wfc2_t,  3072, 768);

  ln_k<<<MTOT_, 256, 0, stream>>>(x, ln1g, ln1b, hbuf);

  // QKV: [18464,768] x [768,2304]
  gemm_bt<0><<<dim3(145, 18), 256, 0, stream>>>(hbuf, wqkv_t, MTOT_, 2304, 768,
      nullptr, nullptr, nullptr, nullptr, qbuf, kbuf, vtbuf);

  attn_k<<<dim3(384, 10), 256, 0, stream>>>(qbuf, kbuf, vtbuf, mask, obuf);

  // proj + bias + residual(x) -> d_out (fp32)
  gemm_bt<1><<<dim3(145, 6), 256, 0, stream>>>(obuf, wproj_t, MTOT_, 768, 768,
      bproj, x, out, nullptr, nullptr, nullptr, nullptr);

  ln_k<<<MTOT_, 256, 0, stream>>>(out, ln2g, ln2b, h2buf);

  // MLP in two row-chunks so h3 fits the dead k|vt region
  const int M0 = 9216, M1 = MTOT_ - M0;  // 9216 + 9248
  // chunk 0
  gemm_bt<2><<<dim3(72, 24), 256, 0, stream>>>(h2buf, wfc1_t, M0, 3072, 768,
      bfc1, nullptr, nullptr, h3buf, nullptr, nullptr, nullptr);
  gemm_bt<1><<<dim3(72, 6), 256, 0, stream>>>(h3buf, wfc2_t, M0, 768, 3072,
      bfc2, out, out, nullptr, nullptr, nullptr, nullptr);
  // chunk 1
  gemm_bt<2><<<dim3(73, 24), 256, 0, stream>>>(h2buf + (size_t)M0 * 768, wfc1_t, M1, 3072, 768,
      bfc1, nullptr, nullptr, h3buf, nullptr, nullptr, nullptr);
  gemm_bt<1><<<dim3(73, 6), 256, 0, stream>>>(h3buf, wfc2_t, M1, 768, 3072,
      bfc2, out + (size_t)M0 * 768, out + (size_t)M0 * 768, nullptr, nullptr, nullptr, nullptr);
}

// Round 7
// 868.121 us; speedup vs baseline: 1.2792x; 1.0459x over previous
//
#include <hip/hip_runtime.h>
#include <math.h>

typedef unsigned short u16;
typedef unsigned int u32;
typedef __attribute__((ext_vector_type(8))) short bf16x8;   // 8 bf16 in 4 VGPRs
typedef __attribute__((ext_vector_type(4))) float f32x4;

#define B_    32
#define N_    577
#define DIM_  768
#define HEADS_ 12
#define HD_   64
#define HID_  3072
#define MTOT_ (B_*N_)      // 18464
#define NP_   640          // padded key-length for v^T rows

// ---------- bf16 helpers (RNE) ----------
__device__ __forceinline__ u16 f2b(float f){
  u32 u = __builtin_bit_cast(u32, f);
  u += 0x7fffu + ((u >> 16) & 1u);
  return (u16)(u >> 16);
}
// pack two f32 -> two bf16 in one u32 (lo = first arg)
__device__ __forceinline__ u32 cvtpk(float lo, float hi){
  u32 r;
  asm("v_cvt_pk_bf16_f32 %0, %1, %2" : "=v"(r) : "v"(lo), "v"(hi));
  return r;
}

// ---------- async global->LDS (dest must be linear in tid: base + tid*size) ----------
__device__ __forceinline__ void gl_lds16(const void* g, void* l){
  __builtin_amdgcn_global_load_lds(
      (const __attribute__((address_space(1))) u32*)g,
      (__attribute__((address_space(3))) u32*)l, 16, 0, 0);
}
__device__ __forceinline__ void gl_lds4(const void* g, void* l){
  __builtin_amdgcn_global_load_lds(
      (const __attribute__((address_space(1))) u32*)g,
      (__attribute__((address_space(3))) u32*)l, 4, 0, 0);
}

// ---------- weight convert + transpose: w[K][N] fp32 -> wt[N][K] bf16 ----------
__global__ __launch_bounds__(256) void convT(const float* __restrict__ w,
                                             u16* __restrict__ wt, int K, int N){
  __shared__ float t[32][33];
  int n0 = blockIdx.x * 32, k0 = blockIdx.y * 32;
  int tx = threadIdx.x, ty = threadIdx.y;     // block (32,8)
  #pragma unroll
  for (int j = 0; j < 4; ++j)
    t[ty + j*8][tx] = w[(size_t)(k0 + ty + j*8) * N + n0 + tx];
  __syncthreads();
  #pragma unroll
  for (int j = 0; j < 4; ++j)
    wt[(size_t)(n0 + ty + j*8) * K + k0 + tx] = f2b(t[tx][ty + j*8]);
}

// ---------- LayerNorm row kernel: fp32 in -> bf16 out ----------
__global__ __launch_bounds__(256) void ln_k(const float* __restrict__ x,
                                            const float* __restrict__ g,
                                            const float* __restrict__ b,
                                            u16* __restrict__ out){
  int row = blockIdx.x, tid = threadIdx.x;
  const float* xr = x + (size_t)row * DIM_;
  float v0 = xr[tid], v1 = xr[tid + 256], v2 = xr[tid + 512];
  float s = v0 + v1 + v2;
  float s2 = v0*v0 + v1*v1 + v2*v2;
  #pragma unroll
  for (int m = 1; m < 64; m <<= 1){ s += __shfl_xor(s, m); s2 += __shfl_xor(s2, m); }
  __shared__ float ws[8];
  int wid = tid >> 6, ln = tid & 63;
  if (ln == 0){ ws[wid] = s; ws[4 + wid] = s2; }
  __syncthreads();
  s  = ws[0] + ws[1] + ws[2] + ws[3];
  s2 = ws[4] + ws[5] + ws[6] + ws[7];
  float mu = s * (1.0f / DIM_);
  float var = s2 * (1.0f / DIM_) - mu * mu;
  float rs = rsqrtf(var + 1e-5f);
  u16* orow = out + (size_t)row * DIM_;
  orow[tid]       = f2b((v0 - mu) * rs * g[tid]       + b[tid]);
  orow[tid + 256] = f2b((v1 - mu) * rs * g[tid + 256] + b[tid + 256]);
  orow[tid + 512] = f2b((v2 - mu) * rs * g[tid + 512] + b[tid + 512]);
}

// ---------- bt-GEMM: 2-phase double-buffered (T3-minimum) + XCD swizzle ----------
// Per ktile: issue next-tile global_load_lds into buf^1 FIRST, then ds_read+MFMA
// on buf[cur], then ONE __syncthreads() (its vmcnt/lgkmcnt drain = stage-complete
// AND read-complete). Overwriting buf^1 is safe: previous iter's barrier proved
// all waves finished reading it.
// EPI 0: QKV scatter | EPI 1: fp32 out = acc + bias + resid | EPI 2: bf16 out = gelu(acc+bias)
#define BM 128
#define BN 128
#define BK 32

template<int EPI>
__global__ __launch_bounds__(256) void gemm_bt(
    const u16* __restrict__ A, const u16* __restrict__ Bt,
    int M, int N, int K,
    const float* __restrict__ bias,
    const float* __restrict__ resid,
    float* __restrict__ outf,
    u16* __restrict__ outb,
    u16* __restrict__ qb, u16* __restrict__ kb, u16* __restrict__ vtb)
{
  __shared__ u16 Al[2][BM * BK];
  __shared__ u16 Bl[2][BN * BK];
  int tid = threadIdx.x;
  int wid = tid >> 6, l = tid & 63, ln = l & 15, sub = l >> 4;
  int wm = wid >> 1, wn = wid & 1;

  // bijective XCD swizzle (m204): contiguous tm-major chunks per XCD
  int nwg  = gridDim.x * gridDim.y;
  int flat = blockIdx.x + gridDim.x * blockIdx.y;
  int q8 = nwg >> 3, r8 = nwg & 7;
  int xcd = flat & 7, j8 = flat >> 3;
  int wgid = (xcd < r8 ? xcd * (q8 + 1) : r8 * (q8 + 1) + (xcd - r8) * q8) + j8;
  int tm = wgid / gridDim.y;
  int tn = wgid - tm * gridDim.y;

  f32x4 acc[4][4] = {};
  int arow = tid >> 2;            // 0..63
  int acol = (tid & 3) * 8;       // 0,8,16,24

  int gr0 = tm * BM + arow;      if (gr0 >= M) gr0 = M - 1;
  int gr1 = tm * BM + arow + 64; if (gr1 >= M) gr1 = M - 1;
  const u16* ga0 = A + (size_t)gr0 * K + acol;
  const u16* ga1 = A + (size_t)gr1 * K + acol;
  const u16* gb0 = Bt + (size_t)(tn * BN + arow) * K + acol;
  const u16* gb1 = Bt + (size_t)(tn * BN + arow + 64) * K + acol;
  int s0 = arow * BK + acol;              // per-thread LDS element offset (lane-linear)
  int s1 = (arow + 64) * BK + acol;

  const int ktiles = K / BK;
  // prologue: stage kt=0 into buf 0
  gl_lds16(ga0, &Al[0][s0]);
  gl_lds16(ga1, &Al[0][s1]);
  gl_lds16(gb0, &Bl[0][s0]);
  gl_lds16(gb1, &Bl[0][s1]);
  __syncthreads();

  int cur = 0;
  for (int kt = 0; kt < ktiles; ++kt){
    int nxt = cur ^ 1;
    if (kt + 1 < ktiles){
      int kb = (kt + 1) * BK;
      gl_lds16(ga0 + kb, &Al[nxt][s0]);
      gl_lds16(ga1 + kb, &Al[nxt][s1]);
      gl_lds16(gb0 + kb, &Bl[nxt][s0]);
      gl_lds16(gb1 + kb, &Bl[nxt][s1]);
    }
    bf16x8 af[4], bfr[4];
    #pragma unroll
    for (int mi = 0; mi < 4; ++mi) af[mi]  = *(const bf16x8*)&Al[cur][(wm*64 + mi*16 + ln) * BK + sub*8];
    #pragma unroll
    for (int ni = 0; ni < 4; ++ni) bfr[ni] = *(const bf16x8*)&Bl[cur][(wn*64 + ni*16 + ln) * BK + sub*8];
    #pragma unroll
    for (int mi = 0; mi < 4; ++mi)
      #pragma unroll
      for (int ni = 0; ni < 4; ++ni)
        acc[mi][ni] = __builtin_amdgcn_mfma_f32_16x16x32_bf16(af[mi], bfr[ni], acc[mi][ni], 0, 0, 0);
    __syncthreads();   // drains this iter's stage (vmcnt) + own ds_reads (lgkmcnt)
    cur = nxt;
  }

  #pragma unroll
  for (int mi = 0; mi < 4; ++mi){
    int rbase = tm * BM + wm * 64 + mi * 16 + sub * 4;
    #pragma unroll
    for (int ni = 0; ni < 4; ++ni){
      int col = tn * BN + wn * 64 + ni * 16 + ln;
      #pragma unroll
      for (int r = 0; r < 4; ++r){
        int grow = rbase + r;
        if (grow >= M) continue;
        float val = acc[mi][ni][r];
        if (EPI == 0){
          u32 bb = (u32)grow / 577u;
          u32 nn = (u32)grow - bb * 577u;
          int which = col / 768;           // 0=q, 1=k, 2=v
          int rem = col - which * 768;     // col % 768 (768 not pow2!)
          int hh = rem >> 6;
          int d  = col & 63;               // ok: 768 % 64 == 0
          if (which == 0)
            qb[(((size_t)bb * HEADS_ + hh) * N_ + nn) * HD_ + d] = f2b(val);
          else if (which == 1)
            kb[(((size_t)bb * HEADS_ + hh) * N_ + nn) * HD_ + d] = f2b(val);
          else
            vtb[(((size_t)bb * HEADS_ + hh) * HD_ + d) * NP_ + nn] = f2b(val);
        } else if (EPI == 1){
          outf[(size_t)grow * N + col] = val + bias[col] + resid[(size_t)grow * N + col];
        } else {
          float t = val + bias[col];
          float ge = 0.5f * t * (1.0f + erff(t * 0.70710678118654752f));
          outb[(size_t)grow * N + col] = f2b(ge);
        }
      }
    }
  }
}

// ---------- fused flash attention, swapped-QK^T layout ----------
// grid: x = b*h (384) -> flat%8 = bh%8, all q-tiles of a bh share an XCD L2.
//       y = q-tile (10). 4 waves, each owns 16 q-rows; each LANE owns 1 q-row.
// Swapped mfma(K,Q): S^T layout -> lane(ln,sub) holds S[k=c*16+sub*4+r][q=ln].
// Softmax reduce = 2 shfl_xor (x16, x32) on scalars. P packed via cvt_pk into
// per-wave LDS (row = q = ln), read back as A-frag for PV.
__global__ __launch_bounds__(256) void attn_k(
    const u16* __restrict__ q, const u16* __restrict__ k,
    const u16* __restrict__ vt, const float* __restrict__ mask,
    u16* __restrict__ o)
{
  const float SCALE = 0.125f;
  int bh = blockIdx.x, qt = blockIdx.y;
  int tid = threadIdx.x;
  int wid = tid >> 6, l = tid & 63, ln = l & 15, sub = l >> 4;
  int b = bh / HEADS_, hh = bh - b * HEADS_;
  int qrow0_blk = qt * 64;
  int qrow0 = qrow0_blk + wid * 16;

  __shared__ u16 Kl[64 * 64];     // [kr][d], chunk-XOR swizzled, 8KB
  __shared__ u16 Vl[64 * 64];     // [d][kv], chunk-XOR swizzled, 8KB
  __shared__ float Ml[64 * 64];   // mask [q][kv], fp32-chunk-XOR swizzled, 16KB
  __shared__ u16 Pl[4][16 * 64];  // per-wave P [q=ln][k], chunk-XOR swizzled, 8KB

  int qr = qrow0 + ln; if (qr > N_ - 1) qr = N_ - 1;
  const u16* qbase = q + ((size_t)bh * N_ + qr) * HD_;
  bf16x8 qf0 = *(const bf16x8*)&qbase[sub * 8];        // B-frag: Q[q=ln][d=sub*8+j]
  bf16x8 qf1 = *(const bf16x8*)&qbase[32 + sub * 8];

  f32x4 oacc[4] = {};
  float mrun = -1e30f, lrun = 0.f;

  for (int mt = 0; mt < 10; ++mt){
    int mbase = mt * 64;
    // ---- stage K, V (pre-swizzled source, 16B chunk ^ row&7) ----
    #pragma unroll
    for (int p = 0; p < 2; ++p){
      int row = (tid >> 3) + p * 32;
      int sc = (tid & 7) ^ (row & 7);
      int kr = mbase + row; if (kr > N_ - 1) kr = N_ - 1;
      gl_lds16(&k[((size_t)bh * N_ + kr) * HD_ + sc * 8], &Kl[row * 64 + (tid & 7) * 8]);
      gl_lds16(&vt[((size_t)bh * HD_ + row) * NP_ + mbase + sc * 8], &Vl[row * 64 + (tid & 7) * 8]);
    }
    // ---- stage mask with fp32 chunk-XOR swizzle: phys chunk = logical ^ (row&15) ----
    if (mbase + 63 < N_){
      #pragma unroll
      for (int p = 0; p < 4; ++p){
        int row = (tid >> 4) + p * 16;
        int grow = qrow0_blk + row; if (grow > N_ - 1) grow = N_ - 1;
        int sc = (tid & 15) ^ (row & 15);           // pre-swizzled source chunk (4 floats)
        gl_lds16(&mask[(size_t)grow * N_ + mbase + sc * 4], &Ml[row * 64 + (tid & 15) * 4]);
      }
    } else {
      // ragged last tile: per-float staging; value at phys (row,kp) comes from
      // logical col ((kp>>2)^(row&15))*4 + (kp&3), clamped
      #pragma unroll
      for (int p = 0; p < 16; ++p){
        int row = (tid >> 6) + p * 4;
        int grow = qrow0_blk + row; if (grow > N_ - 1) grow = N_ - 1;
        int kp = tid & 63;
        int lcol = ((((kp >> 2) ^ (row & 15)) << 2) | (kp & 3));
        int gcol = mbase + lcol; if (gcol > N_ - 1) gcol = N_ - 1;
        gl_lds4(&mask[(size_t)grow * N_ + gcol], &Ml[row * 64 + kp]);
      }
    }
    __syncthreads();

    // ---- QK^T (swapped): s[c] lane(ln,sub) reg r = S[k=c*16+sub*4+r][q=ln] ----
    f32x4 s[4];
    #pragma unroll
    for (int c = 0; c < 4; ++c){
      int krow = c * 16 + ln;
      bf16x8 kf0 = *(const bf16x8*)&Kl[krow * 64 + ((sub    ) ^ (krow & 7)) * 8];
      bf16x8 kf1 = *(const bf16x8*)&Kl[krow * 64 + ((4 + sub) ^ (krow & 7)) * 8];
      f32x4 z = {};
      z = __builtin_amdgcn_mfma_f32_16x16x32_bf16(kf0, qf0, z, 0, 0, 0);
      z = __builtin_amdgcn_mfma_f32_16x16x32_bf16(kf1, qf1, z, 0, 0, 0);
      s[c] = z;
    }
    // ---- scale * mask: lane needs mask[q=ln(row in block)][k=c*16+sub*4+r] ----
    int mrow = wid * 16 + ln;
    #pragma unroll
    for (int c = 0; c < 4; ++c){
      f32x4 mv = *(const f32x4*)&Ml[mrow * 64 + (((c * 4 + sub) ^ ln) << 2)];
      int mg0 = mbase + c * 16 + sub * 4;
      #pragma unroll
      for (int r = 0; r < 4; ++r){
        if (mg0 + r < N_) s[c][r] = s[c][r] * SCALE * mv[r];
        else              s[c][r] = -1e30f;
      }
    }
    // ---- online softmax: row q=ln lives on lanes {ln, ln+16, ln+32, ln+48} ----
    float pm = s[0][0];
    #pragma unroll
    for (int c = 0; c < 4; ++c)
      #pragma unroll
      for (int r = 0; r < 4; ++r) pm = fmaxf(pm, s[c][r]);
    pm = fmaxf(pm, __shfl_xor(pm, 16));
    pm = fmaxf(pm, __shfl_xor(pm, 32));
    float mnew = fmaxf(mrun, pm);
    float alpha = __expf(mrun - mnew);
    mrun = mnew;
    float ps = 0.f;
    #pragma unroll
    for (int c = 0; c < 4; ++c)
      #pragma unroll
      for (int r = 0; r < 4; ++r){
        float p = __expf(s[c][r] - mrun);
        s[c][r] = p;
        ps += p;
      }
    ps += __shfl_xor(ps, 16);
    ps += __shfl_xor(ps, 32);
    lrun = lrun * alpha + ps;
    // ---- P pack (cvt_pk) -> per-wave LDS, row = q = ln, chunk-XOR swizzle ----
    #pragma unroll
    for (int c = 0; c < 4; ++c)
      #pragma unroll
      for (int h = 0; h < 2; ++h){
        int kk = c * 16 + sub * 4 + 2 * h;
        u32 w = cvtpk(s[c][2 * h], s[c][2 * h + 1]);
        *(u32*)&Pl[wid][ln * 64 + (((kk >> 3) ^ (ln & 7)) << 3) + (kk & 7)] = w;
      }
    // ---- rescale O: needs alpha at q-row = sub*4+r (D-layout) ----
    float a_d[4];
    #pragma unroll
    for (int r = 0; r < 4; ++r) a_d[r] = __shfl(alpha, sub * 4 + r);
    #pragma unroll
    for (int dt = 0; dt < 4; ++dt)
      #pragma unroll
      for (int r = 0; r < 4; ++r) oacc[dt][r] *= a_d[r];
    // ---- PV: A = P rows (q=ln), B = Vt rows (d) ----
    #pragma unroll
    for (int kbv = 0; kbv < 2; ++kbv){
      bf16x8 pa = *(const bf16x8*)&Pl[wid][ln * 64 + (((kbv * 4 + sub) ^ (ln & 7)) << 3)];
      #pragma unroll
      for (int dt = 0; dt < 4; ++dt){
        int vrow = dt * 16 + ln;
        bf16x8 vf = *(const bf16x8*)&Vl[vrow * 64 + (((kbv * 4 + sub) ^ (vrow & 7)) << 3)];
        oacc[dt] = __builtin_amdgcn_mfma_f32_16x16x32_bf16(pa, vf, oacc[dt], 0, 0, 0);
      }
    }
    __syncthreads();   // all waves done with Kl/Vl/Ml before next stage
  }
  // ---- epilogue: O[q = qrow0 + sub*4 + r][d = dt*16 + ln] ----
  float rinv = 1.0f / lrun;
  float inv_d[4];
  #pragma unroll
  for (int r = 0; r < 4; ++r) inv_d[r] = __shfl(rinv, sub * 4 + r);
  #pragma unroll
  for (int dt = 0; dt < 4; ++dt)
    #pragma unroll
    for (int r = 0; r < 4; ++r){
      int qg = qrow0 + sub * 4 + r;
      if (qg < N_)
        o[((size_t)b * N_ + qg) * DIM_ + hh * HD_ + dt * 16 + ln] = f2b(oacc[dt][r] * inv_d[r]);
    }
}

// ---------- workspace layout (bytes, all 256-aligned) ----------
#define OFF_WQKV  0ull
#define OFF_WPROJ 3538944ull
#define OFF_WFC1  4718592ull
#define OFF_WFC2  9437184ull
#define OFF_BUFA  14155776ull                       // h (LN1 out), then attn O
#define OFF_BUFB  (OFF_BUFA + 28360704ull)          // q, then h2 (LN2 out)
#define OFF_BUFC  (OFF_BUFB + 28360704ull)          // k | vt, then h3 (fc1 out)
#define OFF_VT    (OFF_BUFC + 28360704ull)
// total ≈ 130.7 MB

extern "C" void kernel_launch(void* const* d_in, const int* in_sizes, int n_in,
                              void* d_out, int out_size, void* d_ws, size_t ws_size,
                              hipStream_t stream)
{
  const float* x     = (const float*)d_in[0];
  const float* mask  = (const float*)d_in[1];
  const float* ln1g  = (const float*)d_in[2];
  const float* ln1b  = (const float*)d_in[3];
  const float* wqkv  = (const float*)d_in[4];
  const float* wproj = (const float*)d_in[5];
  const float* bproj = (const float*)d_in[6];
  const float* ln2g  = (const float*)d_in[7];
  const float* ln2b  = (const float*)d_in[8];
  const float* wfc1  = (const float*)d_in[9];
  const float* bfc1  = (const float*)d_in[10];
  const float* wfc2  = (const float*)d_in[11];
  const float* bfc2  = (const float*)d_in[12];
  float* out = (float*)d_out;

  char* ws = (char*)d_ws;
  u16* wqkv_t  = (u16*)(ws + OFF_WQKV);
  u16* wproj_t = (u16*)(ws + OFF_WPROJ);
  u16* wfc1_t  = (u16*)(ws + OFF_WFC1);
  u16* wfc2_t  = (u16*)(ws + OFF_WFC2);
  u16* hbuf  = (u16*)(ws + OFF_BUFA);   // LN1 out
  u16* obuf  = (u16*)(ws + OFF_BUFA);   // attn out (reuses h)
  u16* qbuf  = (u16*)(ws + OFF_BUFB);
  u16* h2buf = (u16*)(ws + OFF_BUFB);   // LN2 out (reuses q)
  u16* kbuf  = (u16*)(ws + OFF_BUFC);
  u16* vtbuf = (u16*)(ws + OFF_VT);
  u16* h3buf = (u16*)(ws + OFF_BUFC);   // fc1 out chunk (reuses k|vt)

  dim3 tb(32, 8);
  convT<<<dim3(2304/32, 768/32), tb, 0, stream>>>(wqkv,  wqkv_t,  768,  2304);
  convT<<<dim3(768/32,  768/32), tb, 0, stream>>>(wproj, wproj_t, 768,  768);
  convT<<<dim3(3072/32, 768/32), tb, 0, stream>>>(wfc1,  wfc1_t,  768,  3072);
  convT<<<dim3(768/32, 3072/32), tb, 0, stream>>>(wfc2,  wfc2_t,  3072, 768);

  ln_k<<<MTOT_, 256, 0, stream>>>(x, ln1g, ln1b, hbuf);

  // QKV: [18464,768] x [768,2304]
  gemm_bt<0><<<dim3(145, 18), 256, 0, stream>>>(hbuf, wqkv_t, MTOT_, 2304, 768,
      nullptr, nullptr, nullptr, nullptr, qbuf, kbuf, vtbuf);

  attn_k<<<dim3(384, 10), 256, 0, stream>>>(qbuf, kbuf, vtbuf, mask, obuf);

  // proj + bias + residual(x) -> d_out (fp32)
  gemm_bt<1><<<dim3(145, 6), 256, 0, stream>>>(obuf, wproj_t, MTOT_, 768, 768,
      bproj, x, out, nullptr, nullptr, nullptr, nullptr);

  ln_k<<<MTOT_, 256, 0, stream>>>(out, ln2g, ln2b, h2buf);

  // MLP in two row-chunks so h3 fits the dead k|vt region
  const int M0 = 9216, M1 = MTOT_ - M0;  // 9216 + 9248
  // chunk 0
  gemm_bt<2><<<dim3(72, 24), 256, 0, stream>>>(h2buf, wfc1_t, M0, 3072, 768,
      bfc1, nullptr, nullptr, h3buf, nullptr, nullptr, nullptr);
  gemm_bt<1><<<dim3(72, 6), 256, 0, stream>>>(h3buf, wfc2_t, M0, 768, 3072,
      bfc2, out, out, nullptr, nullptr, nullptr, nullptr);
  // chunk 1
  gemm_bt<2><<<dim3(73, 24), 256, 0, stream>>>(h2buf + (size_t)M0 * 768, wfc1_t, M1, 3072, 768,
      bfc1, nullptr, nullptr, h3buf, nullptr, nullptr, nullptr);
  gemm_bt<1><<<dim3(73, 6), 256, 0, stream>>>(h3buf, wfc2_t, M1, 768, 3072,
      bfc2, out + (size_t)M0 * 768, out + (size_t)M0 * 768, nullptr, nullptr, nullptr, nullptr);
}